// Round 2
// baseline (5966.494 us; speedup 1.0000x reference)
//
#include <hip/hip_runtime.h>

// LSTM stack, B=256 rows (one block each), T=1024 steps.
// Round 2 structure: lane-group of SPLIT threads owns unit u (all 4 gate
// columns), k-split across the group. Each thread reads its k-slice of the
// combined [x;h] LDS vector ONCE per step and reuses it for 4 gates
// (4x less LDS traffic than gate-per-thread). Gate sums combined with an
// in-wave shfl_xor butterfly; activations + c/h update in the owning lanes.
// Double-buffered [x;h] -> ONE barrier per step.

#define BATCH 256
#define TSTEPS 1024

__device__ __forceinline__ float sigm(float x) {
    return 1.0f / (1.0f + __expf(-x));
}

__device__ __forceinline__ float tanh_fast(float x) {
    float ax = fabsf(x);
    float e = __expf(2.0f * ax);
    float r = 1.0f - 2.0f / (e + 1.0f);
    return copysignf(r, x);
}

template<int DIN, int U, int SPLIT, int BLOCK, bool LAST>
__global__ __launch_bounds__(BLOCK, 1)
void lstm_layer(const float* __restrict__ xin,   // [B, T, DIN]
                const float* __restrict__ Wx,    // [DIN, 4U]
                const float* __restrict__ Wh,    // [U, 4U]
                const float* __restrict__ bias,  // [4U]
                float* __restrict__ xout,        // [B, T, U] (unused if LAST)
                const float* __restrict__ Wout,  // [U] (LAST only)
                const float* __restrict__ bout,  // [1] (LAST only)
                float* __restrict__ dout)        // [B] (LAST only)
{
    constexpr int G    = 4 * U;
    constexpr int K    = DIN + U;                       // combined [x;h] length
    constexpr int KSEG = (((K + SPLIT - 1) / SPLIT) + 3) & ~3;  // per-lane slice, x4 aligned
    constexpr int KP   = KSEG * SPLIT;                  // padded buffer length

    const int b   = blockIdx.x;
    const int tid = threadIdx.x;
    const int u   = tid / SPLIT;     // unit owned by this lane-group
    const int s   = tid % SPLIT;     // k-segment within the group
    const bool active = (u < U);

    __shared__ __align__(16) float s_xh[2][KP];

    // zero both buffers: initial h = 0, pad region must be non-NaN
    for (int i = tid; i < 2 * KP; i += BLOCK) ((float*)s_xh)[i] = 0.0f;

    // ---- weights for this lane's k-slice of unit u's 4 gate columns ----
    float w[4][KSEG];
    float bj[4];
#pragma unroll
    for (int g = 0; g < 4; ++g) {
        const int col = g * U + (active ? u : 0);
        bj[g] = active ? bias[col] : 0.0f;
#pragma unroll
        for (int kk = 0; kk < KSEG; ++kk) {
            const int k = s * KSEG + kk;
            float v = 0.0f;
            if (active) {
                if (k < DIN)      v = Wx[k * G + col];
                else if (k < K)   v = Wh[(k - DIN) * G + col];
            }
            w[g][kk] = v;
        }
    }

    const float* xrow = xin + (size_t)b * TSTEPS * DIN;
    if (tid < DIN) s_xh[0][tid] = xrow[tid];   // x_0
    __syncthreads();

    float c = 0.0f;
    float h = 0.0f;
    int cur = 0;

    for (int t = 0; t < TSTEPS; ++t, cur ^= 1) {
        // prefetch x_{t+1} (latency hides under the dot phase)
        float xn = 0.0f;
        if (tid < DIN && t + 1 < TSTEPS) xn = xrow[(size_t)(t + 1) * DIN + tid];

        // ---- partial dots over this lane's k-slice, reused for 4 gates ----
        float acc0 = 0.0f, acc1 = 0.0f, acc2 = 0.0f, acc3 = 0.0f;
        const float* xh = &s_xh[cur][s * KSEG];
#pragma unroll
        for (int kk = 0; kk < KSEG; kk += 4) {
            float4 v = *(const float4*)(xh + kk);
            acc0 = fmaf(v.x, w[0][kk + 0], acc0);
            acc0 = fmaf(v.y, w[0][kk + 1], acc0);
            acc0 = fmaf(v.z, w[0][kk + 2], acc0);
            acc0 = fmaf(v.w, w[0][kk + 3], acc0);
            acc1 = fmaf(v.x, w[1][kk + 0], acc1);
            acc1 = fmaf(v.y, w[1][kk + 1], acc1);
            acc1 = fmaf(v.z, w[1][kk + 2], acc1);
            acc1 = fmaf(v.w, w[1][kk + 3], acc1);
            acc2 = fmaf(v.x, w[2][kk + 0], acc2);
            acc2 = fmaf(v.y, w[2][kk + 1], acc2);
            acc2 = fmaf(v.z, w[2][kk + 2], acc2);
            acc2 = fmaf(v.w, w[2][kk + 3], acc2);
            acc3 = fmaf(v.x, w[3][kk + 0], acc3);
            acc3 = fmaf(v.y, w[3][kk + 1], acc3);
            acc3 = fmaf(v.z, w[3][kk + 2], acc3);
            acc3 = fmaf(v.w, w[3][kk + 3], acc3);
        }

        // ---- butterfly combine across the SPLIT lanes of this group ----
#pragma unroll
        for (int d = 1; d < SPLIT; d <<= 1) {
            acc0 += __shfl_xor(acc0, d, 64);
            acc1 += __shfl_xor(acc1, d, 64);
            acc2 += __shfl_xor(acc2, d, 64);
            acc3 += __shfl_xor(acc3, d, 64);
        }

        const float gi = acc0 + bj[0];
        const float gf = acc1 + bj[1];
        const float gc = acc2 + bj[2];
        const float go = acc3 + bj[3];

        const float fi = sigm(gi);
        const float ff = sigm(gf);
        const float fo = sigm(go);
        c = ff * c + fi * tanh_fast(gc);
        h = fo * tanh_fast(c);

        const int nxt = cur ^ 1;
        if (active && s == 0) {
            s_xh[nxt][DIN + u] = h;
            if (!LAST) xout[((size_t)b * TSTEPS + t) * U + u] = h;
        }
        if (tid < DIN) s_xh[nxt][tid] = xn;
        __syncthreads();   // next step's buffer complete; cur buffer now free
    }

    if (LAST && tid == 0) {
        // final h lives in s_xh[cur][DIN..DIN+U) (cur == TSTEPS&1 after loop)
        float acc = bout[0];
#pragma unroll
        for (int k = 0; k < U; ++k) acc = fmaf(s_xh[cur][DIN + k], Wout[k], acc);
        dout[b] = acc;
    }
}

extern "C" void kernel_launch(void* const* d_in, const int* in_sizes, int n_in,
                              void* d_out, int out_size, void* d_ws, size_t ws_size,
                              hipStream_t stream)
{
    const float* seq  = (const float*)d_in[0];
    const float* Wx0  = (const float*)d_in[1];
    const float* Wh0  = (const float*)d_in[2];
    const float* b0   = (const float*)d_in[3];
    const float* Wx1  = (const float*)d_in[4];
    const float* Wh1  = (const float*)d_in[5];
    const float* b1   = (const float*)d_in[6];
    const float* Wx2  = (const float*)d_in[7];
    const float* Wh2  = (const float*)d_in[8];
    const float* b2   = (const float*)d_in[9];
    const float* Wx3  = (const float*)d_in[10];
    const float* Wh3  = (const float*)d_in[11];
    const float* b3   = (const float*)d_in[12];
    const float* Wout = (const float*)d_in[13];
    const float* bout = (const float*)d_in[14];
    float* out = (float*)d_out;

    float* ws = (float*)d_ws;
    float* X1 = ws;                                   // [256,1024,100]
    float* X2 = ws + (size_t)BATCH * TSTEPS * 100;    // [256,1024,80]
    float* X3 = ws;                                   // [256,1024,50] reuses X1

    dim3 grid(BATCH);

    // SPLIT=2 for big-K layers (register-bound), SPLIT=4 for small layers
    lstm_layer<64, 100, 2, 256, false><<<grid, 256, 0, stream>>>(
        seq, Wx0, Wh0, b0, X1, nullptr, nullptr, nullptr);
    lstm_layer<100, 80, 2, 192, false><<<grid, 192, 0, stream>>>(
        X1, Wx1, Wh1, b1, X2, nullptr, nullptr, nullptr);
    lstm_layer<80, 50, 4, 256, false><<<grid, 256, 0, stream>>>(
        X2, Wx2, Wh2, b2, X3, nullptr, nullptr, nullptr);
    lstm_layer<50, 30, 4, 128, true><<<grid, 128, 0, stream>>>(
        X3, Wx3, Wh3, b3, nullptr, Wout, bout, out);
}

// Round 3
// 3586.325 us; speedup vs baseline: 1.6637x; 1.6637x over previous
//
#include <hip/hip_runtime.h>

// LSTM stack, B=256 rows (one block each), T=1024 steps.
// Round 3: thread owns the 4 gate columns of ONE unit, K split across
// SPLIT=4 consecutive lanes (per-thread weights = 4*S <= 192 floats -> fits
// in the 256 arch-VGPR file, NO scratch spill, unlike rounds 1-2).
// Partial dots reduced with 2 shfl_down stages inside the 4-lane group;
// lane s==0 does activations + c/h update. Double-buffered [x;h] in LDS,
// ONE barrier per step.

#define BATCH 256
#define TSTEPS 1024

__device__ __forceinline__ float sigm(float x) {
    return 1.0f / (1.0f + __expf(-x));
}

__device__ __forceinline__ float tanh_fast(float x) {
    float ax = fabsf(x);
    float e = __expf(2.0f * ax);
    float r = 1.0f - 2.0f / (e + 1.0f);
    return copysignf(r, x);
}

// DIN: input width, U: units, SPLIT: lanes per unit (k-slices),
// S: padded slice length (mult of 4, SPLIT*S >= DIN+U), BLOCK >= U*SPLIT.
template<int DIN, int U, int SPLIT, int S, int BLOCK, bool LAST>
__global__ __launch_bounds__(BLOCK, 1)
void lstm_layer(const float* __restrict__ xin,   // [B, T, DIN]
                const float* __restrict__ Wx,    // [DIN, 4U]
                const float* __restrict__ Wh,    // [U, 4U]
                const float* __restrict__ bias,  // [4U]
                float* __restrict__ xout,        // [B, T, U] (unless LAST)
                const float* __restrict__ Wout,  // [U] (LAST only)
                const float* __restrict__ bout,  // [1] (LAST only)
                float* __restrict__ dout)        // [B] (LAST only)
{
    constexpr int G  = 4 * U;
    constexpr int K  = DIN + U;
    constexpr int KP = SPLIT * S;
    static_assert(KP >= K, "slice coverage");
    static_assert((S % 4) == 0, "float4 alignment");

    const int b   = blockIdx.x;
    const int tid = threadIdx.x;
    const int u   = tid / SPLIT;          // unit owned by this 4-lane group
    const int s   = tid % SPLIT;          // k-slice within the group
    const bool active = (u < U);
    const int uu  = active ? u : 0;       // clamp for safe (unused) loads

    __shared__ __align__(16) float s_xh[2][KP];

    // zero both buffers: h0 = 0, pad region [K..KP) must stay 0 forever
    for (int i = tid; i < 2 * KP; i += BLOCK) ((float*)s_xh)[i] = 0.0f;

    // ---- this lane's k-slice of its unit's 4 gate columns ----
    float w[4][S];
    float bj[4];
#pragma unroll
    for (int g = 0; g < 4; ++g) {
        const int col = g * U + uu;
        bj[g] = bias[col];
#pragma unroll
        for (int kk = 0; kk < S; ++kk) {
            const int k = s * S + kk;
            float v = 0.0f;
            if (k < DIN)    v = Wx[k * G + col];
            else if (k < K) v = Wh[(k - DIN) * G + col];
            w[g][kk] = v;
        }
    }

    const float* xrow = xin + (size_t)b * TSTEPS * DIN;
    if (tid < DIN) s_xh[0][tid] = xrow[tid];   // x_0
    __syncthreads();

    float c = 0.0f;
    int cur = 0;

    for (int t = 0; t < TSTEPS; ++t, cur ^= 1) {
        // prefetch x_{t+1}; latency hides under the FMA phase
        float xn = 0.0f;
        if (t + 1 < TSTEPS && tid < DIN) xn = xrow[(size_t)(t + 1) * DIN + tid];

        // ---- partial dots over this lane's k-slice (4 gates reuse reads) ----
        float a0 = 0.0f, a1 = 0.0f, a2 = 0.0f, a3 = 0.0f;
        const float* xh = &s_xh[cur][s * S];
#pragma unroll
        for (int kk = 0; kk < S; kk += 4) {
            float4 v = *(const float4*)(xh + kk);
            a0 = fmaf(v.x, w[0][kk + 0], a0);
            a0 = fmaf(v.y, w[0][kk + 1], a0);
            a0 = fmaf(v.z, w[0][kk + 2], a0);
            a0 = fmaf(v.w, w[0][kk + 3], a0);
            a1 = fmaf(v.x, w[1][kk + 0], a1);
            a1 = fmaf(v.y, w[1][kk + 1], a1);
            a1 = fmaf(v.z, w[1][kk + 2], a1);
            a1 = fmaf(v.w, w[1][kk + 3], a1);
            a2 = fmaf(v.x, w[2][kk + 0], a2);
            a2 = fmaf(v.y, w[2][kk + 1], a2);
            a2 = fmaf(v.z, w[2][kk + 2], a2);
            a2 = fmaf(v.w, w[2][kk + 3], a2);
            a3 = fmaf(v.x, w[3][kk + 0], a3);
            a3 = fmaf(v.y, w[3][kk + 1], a3);
            a3 = fmaf(v.z, w[3][kk + 2], a3);
            a3 = fmaf(v.w, w[3][kk + 3], a3);
        }

        // ---- reduce across the SPLIT lanes of this group (to lane s==0) ----
#pragma unroll
        for (int d = SPLIT >> 1; d > 0; d >>= 1) {
            a0 += __shfl_down(a0, d);
            a1 += __shfl_down(a1, d);
            a2 += __shfl_down(a2, d);
            a3 += __shfl_down(a3, d);
        }

        const int nxt = cur ^ 1;
        if (active && s == 0) {
            const float fi = sigm(a0 + bj[0]);
            const float ff = sigm(a1 + bj[1]);
            const float tc = tanh_fast(a2 + bj[2]);
            const float fo = sigm(a3 + bj[3]);
            c = ff * c + fi * tc;
            const float h = fo * tanh_fast(c);
            s_xh[nxt][DIN + u] = h;
            if (!LAST) xout[((size_t)b * TSTEPS + t) * U + u] = h;
        }
        if (tid < DIN) s_xh[nxt][tid] = xn;
        __syncthreads();   // nxt buffer complete; cur buffer free for reuse
    }

    if (LAST && tid == 0) {
        // after the loop, cur indexes the buffer holding h_T
        float acc = bout[0];
#pragma unroll
        for (int k = 0; k < U; ++k) acc = fmaf(s_xh[cur][DIN + k], Wout[k], acc);
        dout[b] = acc;
    }
}

extern "C" void kernel_launch(void* const* d_in, const int* in_sizes, int n_in,
                              void* d_out, int out_size, void* d_ws, size_t ws_size,
                              hipStream_t stream)
{
    const float* seq  = (const float*)d_in[0];
    const float* Wx0  = (const float*)d_in[1];
    const float* Wh0  = (const float*)d_in[2];
    const float* b0   = (const float*)d_in[3];
    const float* Wx1  = (const float*)d_in[4];
    const float* Wh1  = (const float*)d_in[5];
    const float* b1   = (const float*)d_in[6];
    const float* Wx2  = (const float*)d_in[7];
    const float* Wh2  = (const float*)d_in[8];
    const float* b2   = (const float*)d_in[9];
    const float* Wx3  = (const float*)d_in[10];
    const float* Wh3  = (const float*)d_in[11];
    const float* b3   = (const float*)d_in[12];
    const float* Wout = (const float*)d_in[13];
    const float* bout = (const float*)d_in[14];
    float* out = (float*)d_out;

    float* ws = (float*)d_ws;
    float* X1 = ws;                                   // [256,1024,100]
    float* X2 = ws + (size_t)BATCH * TSTEPS * 100;    // [256,1024,80]
    float* X3 = ws;                                   // [256,1024,50] reuses X1

    dim3 grid(BATCH);

    // K = DIN+U:      164          180          130         80
    // per-thread wts: 176          192          144         80   (all < 256 arch VGPRs)
    lstm_layer<64, 100, 4, 44, 448, false><<<grid, 448, 0, stream>>>(
        seq, Wx0, Wh0, b0, X1, nullptr, nullptr, nullptr);
    lstm_layer<100, 80, 4, 48, 320, false><<<grid, 320, 0, stream>>>(
        X1, Wx1, Wh1, b1, X2, nullptr, nullptr, nullptr);
    lstm_layer<80, 50, 4, 36, 256, false><<<grid, 256, 0, stream>>>(
        X2, Wx2, Wh2, b2, X3, nullptr, nullptr, nullptr);
    lstm_layer<50, 30, 4, 20, 128, true><<<grid, 128, 0, stream>>>(
        X3, Wx3, Wh3, b3, nullptr, Wout, bout, out);
}